// Round 10
// baseline (394.119 us; speedup 1.0000x reference)
//
#include <hip/hip_runtime.h>

// AttentionBlock: x[4,2048,1024] fp32; scores = x@(Wq@Wk^T)@x^T (NO scale);
// softmax; out = P@(x@Wv).
// M' = Wk@Wq^T -> y = x@M'^T replaces both q,k projections; scores = y@x^T.
// Split-f16 (hi+lo, 3-MFMA) for M', y, scores; plain f16 for v, PV.
// Round 19: scores_c3 v2 — (a) product-major MFMA order (the 3 products of
// acc[m][n] were adjacent = dependent distance 1; now separated by 4 indep
// ops; numerics identical, per-acc order stays hh->hl->lh), applied also to
// yv y-role and gemm_split; (b) staging back to global_load_lds: at ONE
// barrier per step the drain is covered by the ~900cyc MFMA phase (r9/m97
// regime), and dropping 8 ds_write/thread removes ~770 cyc/step of LDS
// write-instr time + the VMEM->VGPR round-trip. Sources keep the inverse
// chunk swizzle (g0/g1), dest linear tid*16 (rule-21: both-sides).
// r10-12's gload_lds failure was 8 drains/TILE; 1 drain/step != that.
// Confirmed dead ends: 128x256 tiles (r4/r5), 32x32x16 MFMA (r6), direct
// lo loads (r7), "memory"-clobber barriers (r11), multi-barrier gload_lds
// pipelines (r10-r12), explicit lgkmcnt(0)/phase (r13), schedule variants
// (r14-r16), 16-wave small tiles (r17: LDS-instr bound), c3 structure
// box: wave-tile 128x64 caps at 2 waves/SIMD (248 regs), 64x64 doubles
// LDS amplification — both ~100µs; c3+3-MFMA = best (r18).

typedef _Float16 half4_t __attribute__((ext_vector_type(4)));
typedef _Float16 half8_t __attribute__((ext_vector_type(8)));
typedef float f32x4 __attribute__((ext_vector_type(4)));

#define BM 128
#define BN 128
#define BK 32

__device__ __forceinline__ void gl_lds16(const _Float16* g, _Float16* l) {
    __builtin_amdgcn_global_load_lds(
        (const __attribute__((address_space(1))) unsigned int*)g,
        (__attribute__((address_space(3))) unsigned int*)l, 16, 0, 0);
}

// ---------------- merged conversion kernel (flat 1D grid) ----------------
__global__ __launch_bounds__(256) void conv_all_kernel(
    const float* __restrict__ x, const float* __restrict__ wq,
    const float* __restrict__ wk, const float* __restrict__ wv,
    _Float16* __restrict__ xh, _Float16* __restrict__ xl,
    _Float16* __restrict__ qh, _Float16* __restrict__ ql,
    _Float16* __restrict__ kh, _Float16* __restrict__ kl,
    _Float16* __restrict__ vTh)
{
    __shared__ float tle[64][65];
    const int bid = blockIdx.x;
    if (bid < 10240) {
        const float* in;
        _Float16 *hi, *lo;
        int i0;
        if (bid < 8192)      { in = x;  hi = xh; lo = xl; i0 = bid; }
        else if (bid < 9216) { in = wq; hi = qh; lo = ql; i0 = bid - 8192; }
        else                 { in = wk; hi = kh; lo = kl; i0 = bid - 9216; }
        int i = i0 * 256 + threadIdx.x;
        float4 v = ((const float4*)in)[i];
        float xs[4] = {v.x, v.y, v.z, v.w};
        half4_t h, l;
#pragma unroll
        for (int j = 0; j < 4; ++j) {
            _Float16 hh = (_Float16)xs[j];
            h[j] = hh;
            l[j] = (_Float16)(xs[j] - (float)hh);
        }
        ((half4_t*)hi)[i] = h;
        ((half4_t*)lo)[i] = l;
    } else {
        const int t = bid - 10240;
        const int tr = (t >> 4) * 64, tc = (t & 15) * 64;
        const int t16 = threadIdx.x & 15, tq = threadIdx.x >> 4;
#pragma unroll
        for (int j = 0; j < 4; ++j) {
            int lr = tq + j * 16;
            float4 v = *(const float4*)(wv + (size_t)(tr + lr) * 1024 + tc + t16 * 4);
            tle[lr][t16 * 4 + 0] = v.x;
            tle[lr][t16 * 4 + 1] = v.y;
            tle[lr][t16 * 4 + 2] = v.z;
            tle[lr][t16 * 4 + 3] = v.w;
        }
        __syncthreads();
#pragma unroll
        for (int j = 0; j < 4; ++j) {
            int orow = tq + j * 16;
            int oc = t16 * 4;
            half4_t h;
#pragma unroll
            for (int i = 0; i < 4; ++i) h[i] = (_Float16)tle[oc + i][orow];
            *(half4_t*)(vTh + (size_t)(tc + orow) * 1024 + tr + oc) = h;
        }
    }
}

// ---------------- split-f16 GEMM (3-MFMA, 16x16x32), 128x128 (M' only) ----------------
template <bool OUTF32>
__global__ __launch_bounds__(256) void gemm_split(
    const _Float16* __restrict__ Ah, const _Float16* __restrict__ Al, size_t az,
    const _Float16* __restrict__ Bh, const _Float16* __restrict__ Bl, size_t bz,
    float* __restrict__ Cf, size_t cz, int ldc,
    _Float16* __restrict__ Oh, _Float16* __restrict__ Ol, size_t oz, int ldo,
    int lda, int ldb, int K)
{
    __shared__ __align__(16) _Float16 sAh[BM][BK], sAl[BM][BK];
    __shared__ __align__(16) _Float16 sBh[BN][BK], sBl[BN][BK];

    const int tid = threadIdx.x;
    const int wave = tid >> 6, lane = tid & 63;
    const int wm = (wave >> 1) * 64, wn = (wave & 1) * 64;
    const int lrow = lane & 15, quad = lane >> 4;
    const int bm = blockIdx.y * BM, bn = blockIdx.x * BN;
    const int z = blockIdx.z;

    const _Float16* pAh = Ah + (size_t)z * az;
    const _Float16* pAl = Al + (size_t)z * az;
    const _Float16* pBh = Bh + (size_t)z * bz;
    const _Float16* pBl = Bl + (size_t)z * bz;

    const int r0 = wave * 32 + (lane >> 2);
    const int kofs = (lane & 3) * 8;
    const size_t a0o = (size_t)(bm + r0) * lda + kofs;
    const size_t a1o = a0o + (size_t)16 * lda;
    const size_t b0o = (size_t)(bn + r0) * ldb + kofs;
    const size_t b1o = b0o + (size_t)16 * ldb;
    _Float16* lA0 = &sAh[r0][kofs];
    _Float16* lA1 = &sAh[r0 + 16][kofs];
    _Float16* lAl0 = &sAl[r0][kofs];
    _Float16* lAl1 = &sAl[r0 + 16][kofs];
    _Float16* lB0 = &sBh[r0][kofs];
    _Float16* lB1 = &sBh[r0 + 16][kofs];
    _Float16* lBl0 = &sBl[r0][kofs];
    _Float16* lBl1 = &sBl[r0 + 16][kofs];

    f32x4 acc[4][4];
#pragma unroll
    for (int i = 0; i < 4; ++i)
#pragma unroll
        for (int j = 0; j < 4; ++j) acc[i][j] = 0.0f;

    for (int k0 = 0; k0 < K; k0 += BK) {
        gl_lds16(pAh + a0o + k0, lA0);
        gl_lds16(pAh + a1o + k0, lA1);
        gl_lds16(pAl + a0o + k0, lAl0);
        gl_lds16(pAl + a1o + k0, lAl1);
        gl_lds16(pBh + b0o + k0, lB0);
        gl_lds16(pBh + b1o + k0, lB1);
        gl_lds16(pBl + b0o + k0, lBl0);
        gl_lds16(pBl + b1o + k0, lBl1);
        __syncthreads();

        half8_t a0[4], a1[4], b0[4], b1[4];
#pragma unroll
        for (int mt = 0; mt < 4; ++mt) {
            a0[mt] = *(const half8_t*)&sAh[wm + mt * 16 + lrow][quad * 8];
            a1[mt] = *(const half8_t*)&sAl[wm + mt * 16 + lrow][quad * 8];
        }
#pragma unroll
        for (int nt = 0; nt < 4; ++nt) {
            b0[nt] = *(const half8_t*)&sBh[wn + nt * 16 + lrow][quad * 8];
            b1[nt] = *(const half8_t*)&sBl[wn + nt * 16 + lrow][quad * 8];
        }
        // product-major: per-acc order stays hh -> hl -> lh (numerics
        // identical); dependent chain links now 16 issues apart.
#pragma unroll
        for (int mt = 0; mt < 4; ++mt)
#pragma unroll
            for (int nt = 0; nt < 4; ++nt)
                acc[mt][nt] = __builtin_amdgcn_mfma_f32_16x16x32_f16(a0[mt], b0[nt], acc[mt][nt], 0, 0, 0);
#pragma unroll
        for (int mt = 0; mt < 4; ++mt)
#pragma unroll
            for (int nt = 0; nt < 4; ++nt)
                acc[mt][nt] = __builtin_amdgcn_mfma_f32_16x16x32_f16(a0[mt], b1[nt], acc[mt][nt], 0, 0, 0);
#pragma unroll
        for (int mt = 0; mt < 4; ++mt)
#pragma unroll
            for (int nt = 0; nt < 4; ++nt)
                acc[mt][nt] = __builtin_amdgcn_mfma_f32_16x16x32_f16(a1[mt], b0[nt], acc[mt][nt], 0, 0, 0);
        __syncthreads();
    }

#pragma unroll
    for (int mt = 0; mt < 4; ++mt)
#pragma unroll
        for (int nt = 0; nt < 4; ++nt)
#pragma unroll
            for (int r = 0; r < 4; ++r) {
                int gm = bm + wm + mt * 16 + quad * 4 + r;
                int gn = bn + wn + nt * 16 + lrow;
                float v = acc[mt][nt][r];
                if (OUTF32) {
                    Cf[(size_t)z * cz + (size_t)gm * ldc + gn] = v;
                } else {
                    _Float16 h = (_Float16)v;
                    Oh[(size_t)z * oz + (size_t)gm * ldo + gn] = h;
                    Ol[(size_t)z * oz + (size_t)gm * ldo + gn] = (_Float16)(v - (float)h);
                }
            }
}

// ---------------- scores: combined 3-MFMA, 256x256 tile, 8 waves, K=1024 ----------------
// v2: gload_lds staging (1 drain/step, covered by MFMA phase) +
// product-major MFMA order. Per step: {read B frags | gload_lds next step
// into other slot | setprio: per m {read A frags; 4xhh; 4xhl; 4xlh} |
// barrier (drains loads -> next slot resident)}.
#define NSTEPS 32  // 1024 / 32

__global__ __launch_bounds__(512, 2) void scores_c3(
    const _Float16* __restrict__ yh, const _Float16* __restrict__ yl,
    const _Float16* __restrict__ xh, const _Float16* __restrict__ xl,
    float* __restrict__ Cf)
{
    __shared__ __align__(16) _Float16 sAh[2][8192], sAl[2][8192];  // 64KB
    __shared__ __align__(16) _Float16 sBh[2][8192], sBl[2][8192];  // 64KB

    const int tid = threadIdx.x;
    const int wave = tid >> 6, lane = tid & 63;
    const int wm = (wave >> 2) * 128;   // 2 wave-rows
    const int wn = (wave & 3) * 64;     // 4 wave-cols
    const int l15 = lane & 15, jq = lane >> 4;

    // XCD-chunked bijective swizzle (256 blocks)
    const int flat = blockIdx.x + (blockIdx.y << 3) + (blockIdx.z << 6);
    const int work = ((flat & 7) << 5) + (flat >> 3);
    const int z = work >> 6;
    const int bm = ((work >> 3) & 7) * 256;
    const int bn = (work & 7) * 256;

    const _Float16* Ah = yh + ((size_t)z * 2048 + bm) * 1024;
    const _Float16* Al = yl + ((size_t)z * 2048 + bm) * 1024;
    const _Float16* Bh = xh + ((size_t)z * 2048 + bn) * 1024;
    const _Float16* Bl = xl + ((size_t)z * 2048 + bn) * 1024;

    // frag LDS byte bases (chunk F = row*4 + (jq ^ ((row>>1)&3)), addr F*16;
    // +16 rows = +1024B immediate, XOR term invariant under +16).
    int a_off0, b_off0;
    {
        int row = wm + l15;
        a_off0 = (row * 4 + (jq ^ ((row >> 1) & 3))) * 16;
        row = wn + l15;
        b_off0 = (row * 4 + (jq ^ ((row >> 1) & 3))) * 16;
    }
    asm volatile("" : "+v"(a_off0), "+v"(b_off0));
    // staging: thread covers chunks c0=tid (rows 0-127) and c1=512+tid
    // (rows 128-255). Source carries the inverse chunk swizzle; LDS dest is
    // linear tid*16 (rule-21 both-sides; layout identical to ds_write wb0).
    int row0 = tid >> 2;
    int j0 = (tid & 3) ^ ((row0 >> 1) & 3);
    int g0 = row0 * 2048 + j0 * 16;   // global byte offset, chunk c0
    int g1 = g0 + 262144;             // +128 rows, chunk c1
    asm volatile("" : "+v"(g0), "+v"(g1));

    // stage step-t panels into slot p via LDS-DMA (8 loads/thread)
    auto GLD = [&](int p, int t) {
        const char* pa = (const char*)(Ah + t * 32);
        const char* pl = (const char*)(Al + t * 32);
        const char* pb = (const char*)(Bh + t * 32);
        const char* pq = (const char*)(Bl + t * 32);
        gl_lds16((const _Float16*)(pa + g0), sAh[p] + tid * 8);
        gl_lds16((const _Float16*)(pa + g1), sAh[p] + 4096 + tid * 8);
        gl_lds16((const _Float16*)(pl + g0), sAl[p] + tid * 8);
        gl_lds16((const _Float16*)(pl + g1), sAl[p] + 4096 + tid * 8);
        gl_lds16((const _Float16*)(pb + g0), sBh[p] + tid * 8);
        gl_lds16((const _Float16*)(pb + g1), sBh[p] + 4096 + tid * 8);
        gl_lds16((const _Float16*)(pq + g0), sBl[p] + tid * 8);
        gl_lds16((const _Float16*)(pq + g1), sBl[p] + 4096 + tid * 8);
    };

    f32x4 acc[8][4];
#pragma unroll
    for (int i = 0; i < 8; ++i)
#pragma unroll
        for (int j = 0; j < 4; ++j) acc[i][j] = 0.0f;

    // one K-32 step: read frags from slot p, DMA step tn into slot p^1,
    // 96 MFMA product-major, barrier (drain).
    auto STEP = [&](int p, int tn) {
        half8_t bhf[4], blf[4];
#pragma unroll
        for (int n = 0; n < 4; ++n) {
            bhf[n] = *(const half8_t*)((const char*)sBh[p] + b_off0 + n * 1024);
            blf[n] = *(const half8_t*)((const char*)sBl[p] + b_off0 + n * 1024);
        }
        GLD(p ^ 1, tn);
        __builtin_amdgcn_s_setprio(1);
#pragma unroll
        for (int m = 0; m < 8; ++m) {
            half8_t ahf = *(const half8_t*)((const char*)sAh[p] + a_off0 + m * 1024);
            half8_t alf = *(const half8_t*)((const char*)sAl[p] + a_off0 + m * 1024);
            // product-major: per-acc order hh -> hl -> lh (numerics
            // identical to r18); dependent links 4 issues apart.
#pragma unroll
            for (int n = 0; n < 4; ++n)
                acc[m][n] = __builtin_amdgcn_mfma_f32_16x16x32_f16(ahf, bhf[n], acc[m][n], 0, 0, 0);
#pragma unroll
            for (int n = 0; n < 4; ++n)
                acc[m][n] = __builtin_amdgcn_mfma_f32_16x16x32_f16(ahf, blf[n], acc[m][n], 0, 0, 0);
#pragma unroll
            for (int n = 0; n < 4; ++n)
                acc[m][n] = __builtin_amdgcn_mfma_f32_16x16x32_f16(alf, bhf[n], acc[m][n], 0, 0, 0);
        }
        __builtin_amdgcn_s_setprio(0);
        __builtin_amdgcn_s_barrier();
    };

    // prologue: DMA step0 into slot0, full drain.
    GLD(0, 0);
    __syncthreads();

    for (int s = 0; s < NSTEPS; s += 2) {
        const int t1 = s + 1;                                  // <= 31
        const int t2 = (s + 2 < NSTEPS) ? s + 2 : NSTEPS - 1;  // clamped dup
        STEP(0, t1);  // read slot0, DMA t1 -> slot1
        STEP(1, t2);  // read slot1, DMA t2 -> slot0
    }

    // epilogue: fp32 C scatter (same mapping as verified gemm_split)
    float* C = Cf + (size_t)z * 2048 * 2048;
#pragma unroll
    for (int mi = 0; mi < 8; ++mi)
#pragma unroll
        for (int ni = 0; ni < 4; ++ni) {
            int gm0 = bm + wm + mi * 16 + jq * 4;
            int gn = bn + wn + ni * 16 + l15;
#pragma unroll
            for (int r = 0; r < 4; ++r)
                C[(size_t)(gm0 + r) * 2048 + gn] = acc[mi][ni][r];
        }
}

// ---------------- merged y-proj (split) + v-proj (plain) kernel ----------------
__global__ __launch_bounds__(256) void yv_kernel(
    const _Float16* __restrict__ xh, const _Float16* __restrict__ xl,
    const _Float16* __restrict__ Mh, const _Float16* __restrict__ Ml,
    const _Float16* __restrict__ wvTh,
    _Float16* __restrict__ yh, _Float16* __restrict__ yl,
    _Float16* __restrict__ vT)
{
    __shared__ __align__(16) char buf[128 * 132 * 2];  // 33792 B

    const int tid = threadIdx.x;
    const int wave = tid >> 6, lane = tid & 63;
    const int wm = (wave >> 1) * 64, wn = (wave & 1) * 64;
    const int lrow = lane & 15, quad = lane >> 4;
    const int bm = blockIdx.y * BM, bn = blockIdx.x * BN;
    const bool vrole = (blockIdx.z != 0);

    const int r0 = wave * 32 + (lane >> 2);
    const int kofs = (lane & 3) * 8;
    const size_t a0o = (size_t)(bm + r0) * 1024 + kofs;
    const size_t a1o = a0o + (size_t)16 * 1024;
    const size_t b0o = (size_t)(bn + r0) * 1024 + kofs;
    const size_t b1o = b0o + (size_t)16 * 1024;

    f32x4 acc[4][4];
#pragma unroll
    for (int i = 0; i < 4; ++i)
#pragma unroll
        for (int j = 0; j < 4; ++j) acc[i][j] = 0.0f;

    _Float16* tle = (_Float16*)buf;

    if (!vrole) {
        _Float16* sAh = (_Float16*)buf;
        _Float16* sAl = (_Float16*)(buf + 8192);
        _Float16* sBh = (_Float16*)(buf + 16384);
        _Float16* sBl = (_Float16*)(buf + 24576);
        _Float16* lA0 = sAh + r0 * BK + kofs;
        _Float16* lA1 = sAh + (r0 + 16) * BK + kofs;
        _Float16* lAl0 = sAl + r0 * BK + kofs;
        _Float16* lAl1 = sAl + (r0 + 16) * BK + kofs;
        _Float16* lB0 = sBh + r0 * BK + kofs;
        _Float16* lB1 = sBh + (r0 + 16) * BK + kofs;
        _Float16* lBl0 = sBl + r0 * BK + kofs;
        _Float16* lBl1 = sBl + (r0 + 16) * BK + kofs;

        for (int k0 = 0; k0 < 1024; k0 += BK) {
            gl_lds16(xh + a0o + k0, lA0);
            gl_lds16(xh + a1o + k0, lA1);
            gl_lds16(xl + a0o + k0, lAl0);
            gl_lds16(xl + a1o + k0, lAl1);
            gl_lds16(Mh + b0o + k0, lB0);
            gl_lds16(Mh + b1o + k0, lB1);
            gl_lds16(Ml + b0o + k0, lBl0);
            gl_lds16(Ml + b1o + k0, lBl1);
            __syncthreads();

            half8_t a0[4], a1[4], b0[4], b1[4];
#pragma unroll
            for (int mt = 0; mt < 4; ++mt) {
                a0[mt] = *(const half8_t*)(sAh + (wm + mt * 16 + lrow) * BK + quad * 8);
                a1[mt] = *(const half8_t*)(sAl + (wm + mt * 16 + lrow) * BK + quad * 8);
            }
#pragma unroll
            for (int nt = 0; nt < 4; ++nt) {
                b0[nt] = *(const half8_t*)(sBh + (wn + nt * 16 + lrow) * BK + quad * 8);
                b1[nt] = *(const half8_t*)(sBl + (wn + nt * 16 + lrow) * BK + quad * 8);
            }
            // product-major (see scores_c3): numerics identical.
#pragma unroll
            for (int mt = 0; mt < 4; ++mt)
#pragma unroll
                for (int nt = 0; nt < 4; ++nt)
                    acc[mt][nt] = __builtin_amdgcn_mfma_f32_16x16x32_f16(a0[mt], b0[nt], acc[mt][nt], 0, 0, 0);
#pragma unroll
            for (int mt = 0; mt < 4; ++mt)
#pragma unroll
                for (int nt = 0; nt < 4; ++nt)
                    acc[mt][nt] = __builtin_amdgcn_mfma_f32_16x16x32_f16(a0[mt], b1[nt], acc[mt][nt], 0, 0, 0);
#pragma unroll
            for (int mt = 0; mt < 4; ++mt)
#pragma unroll
                for (int nt = 0; nt < 4; ++nt)
                    acc[mt][nt] = __builtin_amdgcn_mfma_f32_16x16x32_f16(a1[mt], b0[nt], acc[mt][nt], 0, 0, 0);
            __syncthreads();
        }

#pragma unroll
        for (int pass = 0; pass < 2; ++pass) {
            if (pass) __syncthreads();
#pragma unroll
            for (int mt = 0; mt < 4; ++mt)
#pragma unroll
                for (int nt = 0; nt < 4; ++nt) {
                    int rloc = wm + mt * 16 + quad * 4;
                    int cloc = wn + nt * 16 + lrow;
#pragma unroll
                    for (int r = 0; r < 4; ++r) {
                        float v = acc[mt][nt][r];
                        _Float16 h = (_Float16)v;
                        tle[(rloc + r) * 132 + cloc] =
                            pass == 0 ? h : (_Float16)(v - (float)h);
                    }
                }
            __syncthreads();
            _Float16* dst = pass == 0 ? yh : yl;
#pragma unroll
            for (int i = 0; i < 8; ++i) {
                int flat = i * 256 + tid;
                int rloc = flat >> 4, c = (flat & 15) * 8;
                half8_t o8;
#pragma unroll
                for (int j = 0; j < 8; ++j) o8[j] = tle[rloc * 132 + c + j];
                *(half8_t*)(dst + (size_t)(bm + rloc) * 1024 + bn + c) = o8;
            }
        }
    } else {
        _Float16* sA = (_Float16*)buf;
        _Float16* sB = (_Float16*)(buf + 8192);
        _Float16* lA0 = sA + r0 * BK + kofs;
        _Float16* lA1 = sA + (r0 + 16) * BK + kofs;
        _Float16* lB0 = sB + r0 * BK + kofs;
        _Float16* lB1 = sB + (r0 + 16) * BK + kofs;

        for (int k0 = 0; k0 < 1024; k0 += BK) {
            gl_lds16(xh + a0o + k0, lA0);
            gl_lds16(xh + a1o + k0, lA1);
            gl_lds16(wvTh + b0o + k0, lB0);
            gl_lds16(wvTh + b1o + k0, lB1);
            __syncthreads();

            half8_t a0[4], b0[4];
#pragma unroll
            for (int mt = 0; mt < 4; ++mt)
                a0[mt] = *(const half8_t*)(sA + (wm + mt * 16 + lrow) * BK + quad * 8);
#pragma unroll
            for (int nt = 0; nt < 4; ++nt)
                b0[nt] = *(const half8_t*)(sB + (wn + nt * 16 + lrow) * BK + quad * 8);
#pragma unroll
            for (int mt = 0; mt < 4; ++mt)
#pragma unroll
                for (int nt = 0; nt < 4; ++nt)
                    acc[mt][nt] = __builtin_amdgcn_mfma_f32_16x16x32_f16(a0[mt], b0[nt], acc[mt][nt], 0, 0, 0);
            __syncthreads();
        }

#pragma unroll
        for (int mt = 0; mt < 4; ++mt)
#pragma unroll
            for (int nt = 0; nt < 4; ++nt) {
                int t0 = wm + mt * 16 + quad * 4;
                int e_l = wn + nt * 16 + lrow;
                half4_t o;
#pragma unroll
                for (int r = 0; r < 4; ++r) o[r] = (_Float16)acc[mt][nt][r];
                *(half4_t*)(tle + e_l * 132 + t0) = o;
            }
        __syncthreads();
        const int b = bm >> 11, tb = bm & 2047;
#pragma unroll
        for (int i = 0; i < 8; ++i) {
            int flat = i * 256 + tid;
            int e_l = flat >> 4, c = (flat & 15) * 8;
            half8_t o8;
#pragma unroll
            for (int j = 0; j < 8; ++j) o8[j] = tle[e_l * 132 + c + j];
            *(half8_t*)(vT + ((size_t)b << 21) + (size_t)(bn + e_l) * 2048 + tb + c) = o8;
        }
    }
}

// ---------------- plain-f16 GEMM (16x16x32), 128x128, 256 thr (PV) ----------------
__global__ __launch_bounds__(256) void gemm_plain(
    const _Float16* __restrict__ Ag, size_t az,
    const _Float16* __restrict__ Bg, size_t bz,
    float* __restrict__ Cf, size_t cz, int ldc,
    int lda, int ldb, int K)
{
    __shared__ __align__(16) _Float16 sA[BM][BK], sB[BN][BK];

    const int tid = threadIdx.x;
    const int wave = tid >> 6, lane = tid & 63;
    const int wm = (wave >> 1) * 64, wn = (wave & 1) * 64;
    const int lrow = lane & 15, quad = lane >> 4;
    const int bm = blockIdx.y * BM, bn = blockIdx.x * BN;
    const int z = blockIdx.z;

    const _Float16* pA = Ag + (size_t)z * az;
    const _Float16* pB = Bg + (size_t)z * bz;

    const int r0 = wave * 32 + (lane >> 2);
    const int kofs = (lane & 3) * 8;
    const size_t a0o = (size_t)(bm + r0) * lda + kofs;
    const size_t a1o = a0o + (size_t)16 * lda;
    const size_t b0o = (size_t)(bn + r0) * ldb + kofs;
    const size_t b1o = b0o + (size_t)16 * ldb;
    _Float16* lA0 = &sA[r0][kofs];
    _Float16* lA1 = &sA[r0 + 16][kofs];
    _Float16* lB0 = &sB[r0][kofs];
    _Float16* lB1 = &sB[r0 + 16][kofs];

    f32x4 acc[4][4];
#pragma unroll
    for (int i = 0; i < 4; ++i)
#pragma unroll
        for (int j = 0; j < 4; ++j) acc[i][j] = 0.0f;

    for (int k0 = 0; k0 < K; k0 += BK) {
        gl_lds16(pA + a0o + k0, lA0);
        gl_lds16(pA + a1o + k0, lA1);
        gl_lds16(pB + b0o + k0, lB0);
        gl_lds16(pB + b1o + k0, lB1);
        __syncthreads();

        half8_t a0[4], b0[4];
#pragma unroll
        for (int mt = 0; mt < 4; ++mt)
            a0[mt] = *(const half8_t*)&sA[wm + mt * 16 + lrow][quad * 8];
#pragma unroll
        for (int nt = 0; nt < 4; ++nt)
            b0[nt] = *(const half8_t*)&sB[wn + nt * 16 + lrow][quad * 8];
#pragma unroll
        for (int mt = 0; mt < 4; ++mt)
#pragma unroll
            for (int nt = 0; nt < 4; ++nt)
                acc[mt][nt] = __builtin_amdgcn_mfma_f32_16x16x32_f16(a0[mt], b0[nt], acc[mt][nt], 0, 0, 0);
        __syncthreads();
    }

#pragma unroll
    for (int mt = 0; mt < 4; ++mt)
#pragma unroll
        for (int nt = 0; nt < 4; ++nt) {
            int gm0 = bm + wm + mt * 16 + quad * 4;
            int gn = bn + wn + nt * 16 + lrow;
#pragma unroll
            for (int r = 0; r < 4; ++r)
                Cf[(size_t)z * cz + (size_t)(gm0 + r) * ldc + gn] = acc[mt][nt][r];
        }
}

// ---------------- softmax: fp32 scores row -> f16 P row, in place ----------------
__global__ __launch_bounds__(256) void softmax_kernel(float* __restrict__ S)
{
    float* row = S + (size_t)blockIdx.x * 2048;
    float4* r4 = (float4*)row;
    const int tid = threadIdx.x;
    const int wave = tid >> 6, lane = tid & 63;

    float4 a = r4[tid], b = r4[tid + 256];
    float m = fmaxf(fmaxf(fmaxf(a.x, a.y), fmaxf(a.z, a.w)),
                    fmaxf(fmaxf(b.x, b.y), fmaxf(b.z, b.w)));
#pragma unroll
    for (int o = 32; o; o >>= 1) m = fmaxf(m, __shfl_xor(m, o));
    __shared__ float redm[4];
    __shared__ float reds[4];
    if (lane == 0) redm[wave] = m;
    __syncthreads();
    m = fmaxf(fmaxf(redm[0], redm[1]), fmaxf(redm[2], redm[3]));

    a.x = __expf(a.x - m); a.y = __expf(a.y - m);
    a.z = __expf(a.z - m); a.w = __expf(a.w - m);
    b.x = __expf(b.x - m); b.y = __expf(b.y - m);
    b.z = __expf(b.z - m); b.w = __expf(b.w - m);

    float s = a.x + a.y + a.z + a.w + b.x + b.y + b.z + b.w;
#pragma unroll
    for (int o = 32; o; o >>= 1) s += __shfl_xor(s, o);
    if (lane == 0) reds[wave] = s;
    __syncthreads();
    s = reds[0] + reds[1] + reds[2] + reds[3];

    float inv = 1.0f / s;
    _Float16* o16 = (_Float16*)row;
    half4_t ha, hb;
    ha[0] = (_Float16)(a.x * inv); ha[1] = (_Float16)(a.y * inv);
    ha[2] = (_Float16)(a.z * inv); ha[3] = (_Float16)(a.w * inv);
    hb[0] = (_Float16)(b.x * inv); hb[1] = (_Float16)(b.y * inv);
    hb[2] = (_Float16)(b.z * inv); hb[3] = (_Float16)(b.w * inv);
    ((half4_t*)o16)[tid] = ha;
    ((half4_t*)o16)[tid + 256] = hb;
}

extern "C" void kernel_launch(void* const* d_in, const int* in_sizes, int n_in,
                              void* d_out, int out_size, void* d_ws, size_t ws_size,
                              hipStream_t stream)
{
    const float* x  = (const float*)d_in[0];
    const float* wq = (const float*)d_in[1];
    const float* wk = (const float*)d_in[2];
    const float* wv = (const float*)d_in[3];
    float* out = (float*)d_out;

    const int S = 2048, D = 1024;
    char* ws = (char*)d_ws;

    // ws layout (bytes); high-water 158 MB
    _Float16* xh   = (_Float16*)(ws);                  // 16 MB
    _Float16* xl   = (_Float16*)(ws + (16ull << 20));  // 16 MB
    _Float16* yh   = (_Float16*)(ws + (32ull << 20));  // 16 MB
    _Float16* yl   = (_Float16*)(ws + (48ull << 20));  // 16 MB
    _Float16* vT   = (_Float16*)(ws + (64ull << 20));  // 16 MB [4][1024][2048]
    _Float16* wqh  = (_Float16*)(ws + (80ull << 20));  // 2 MB (natural layout)
    _Float16* wql  = (_Float16*)(ws + (82ull << 20));  // 2 MB
    _Float16* wkh  = (_Float16*)(ws + (84ull << 20));  // 2 MB
    _Float16* wkl  = (_Float16*)(ws + (86ull << 20));  // 2 MB
    _Float16* wvTh = (_Float16*)(ws + (88ull << 20));  // 2 MB (transposed)
    _Float16* Mh   = (_Float16*)(ws + (90ull << 20));  // 2 MB  M' = Wk@Wq^T
    _Float16* Ml   = (_Float16*)(ws + (92ull << 20));  // 2 MB
    float*    sc   = (float*)(ws + (94ull << 20));     // 64 MB scores

    // 1) all conversions, flat grid
    conv_all_kernel<<<dim3(10496), dim3(256), 0, stream>>>(
        x, wq, wk, wv, xh, xl, wqh, wql, wkh, wkl, wvTh);

    // 2) M'[d'][d] = sum_e Wk[d',e]*Wq[d,e]  (split in, split out)
    gemm_split<false><<<dim3(D / BN, D / BM, 1), dim3(256), 0, stream>>>(
        wkh, wkl, 0, wqh, wql, 0, nullptr, 0, 0, Mh, Ml, 0, D, D, D, D);

    // 3) y-proj (split, coalesced epilogue) + v-proj (plain, coalesced vT)
    yv_kernel<<<dim3(D / BN, 8192 / BM, 2), dim3(256), 0, stream>>>(
        xh, xl, Mh, Ml, wvTh, yh, yl, vT);

    // 4) scores: combined 3-MFMA, 256² tile, 8 waves, K=1024, gload_lds
    scores_c3<<<dim3(S / 256, S / 256, 4), dim3(512), 0, stream>>>(
        yh, yl, xh, xl, sc);

    // 5) softmax rows, f16 P written in place (row stride stays 8192 B)
    softmax_kernel<<<dim3(4 * S), dim3(256), 0, stream>>>(sc);

    // 6) out = P @ v: A=P f16 (lda=4096 f16 elems), B=vT f16, out fp32
    gemm_plain<<<dim3(D / BN, S / BM, 4), dim3(256), 0, stream>>>(
        (const _Float16*)sc, (size_t)S * 4096, vT, (size_t)D * S,
        out, (size_t)S * D, D, 4096, S, S);
}

// Round 11
// 366.242 us; speedup vs baseline: 1.0761x; 1.0761x over previous
//
#include <hip/hip_runtime.h>

// AttentionBlock: x[4,2048,1024] fp32; scores = x@(Wq@Wk^T)@x^T (NO scale);
// softmax; out = P@(x@Wv).
// M' = Wk@Wq^T -> y = x@M'^T replaces both q,k projections; scores = y@x^T.
// Split-f16 (hi+lo, 3-MFMA) for M', y, scores; plain f16 for v, PV.
// Round 20: (a) scores reverted to EXACT r18 (reg-staged c3, 96.5 µs best;
// r19's gload_lds+product-major bundle regressed to 100.5), (b) M' split-K:
// r20 budget audit found M' ran 64 blocks on 256 CUs (~30 µs for 6.4 GF).
// Now K=1024 split x4 via unchanged gemm_split<true> (K=256, z-stride 256,
// fp32 partials in 16MB scratch overlapping sc) + reduce_m kernel (sum 4
// partials, split to Mh/Ml). 256 blocks = full GPU; ~13 µs total.
// Scores verdict after r10-r19: per-CU/step = MFMA 3725 + LDS 3072 cyc,
// structurally serial at 1 block/CU; LDS/MFMA ratio fixed by the max wave
// tile (128x64 at AGPR ceiling). ~96 µs is this decomposition's floor.
// Confirmed dead ends: 128x256 tiles (r4/r5), 32x32x16 MFMA (r6), direct
// lo loads (r7), "memory"-clobber barriers (r11), gload_lds in pipelines
// (r10-r12, r19), explicit lgkmcnt(0)/phase (r13), schedule variants
// (r14-r16), 16-wave small tiles (r17), segmented K' (r10-r17 vs c3 r18).

typedef _Float16 half4_t __attribute__((ext_vector_type(4)));
typedef _Float16 half8_t __attribute__((ext_vector_type(8)));
typedef float f32x4 __attribute__((ext_vector_type(4)));

#define BM 128
#define BN 128
#define BK 32

__device__ __forceinline__ void gl_lds16(const _Float16* g, _Float16* l) {
    __builtin_amdgcn_global_load_lds(
        (const __attribute__((address_space(1))) unsigned int*)g,
        (__attribute__((address_space(3))) unsigned int*)l, 16, 0, 0);
}

// ---------------- merged conversion kernel (flat 1D grid) ----------------
__global__ __launch_bounds__(256) void conv_all_kernel(
    const float* __restrict__ x, const float* __restrict__ wq,
    const float* __restrict__ wk, const float* __restrict__ wv,
    _Float16* __restrict__ xh, _Float16* __restrict__ xl,
    _Float16* __restrict__ qh, _Float16* __restrict__ ql,
    _Float16* __restrict__ kh, _Float16* __restrict__ kl,
    _Float16* __restrict__ vTh)
{
    __shared__ float tle[64][65];
    const int bid = blockIdx.x;
    if (bid < 10240) {
        const float* in;
        _Float16 *hi, *lo;
        int i0;
        if (bid < 8192)      { in = x;  hi = xh; lo = xl; i0 = bid; }
        else if (bid < 9216) { in = wq; hi = qh; lo = ql; i0 = bid - 8192; }
        else                 { in = wk; hi = kh; lo = kl; i0 = bid - 9216; }
        int i = i0 * 256 + threadIdx.x;
        float4 v = ((const float4*)in)[i];
        float xs[4] = {v.x, v.y, v.z, v.w};
        half4_t h, l;
#pragma unroll
        for (int j = 0; j < 4; ++j) {
            _Float16 hh = (_Float16)xs[j];
            h[j] = hh;
            l[j] = (_Float16)(xs[j] - (float)hh);
        }
        ((half4_t*)hi)[i] = h;
        ((half4_t*)lo)[i] = l;
    } else {
        const int t = bid - 10240;
        const int tr = (t >> 4) * 64, tc = (t & 15) * 64;
        const int t16 = threadIdx.x & 15, tq = threadIdx.x >> 4;
#pragma unroll
        for (int j = 0; j < 4; ++j) {
            int lr = tq + j * 16;
            float4 v = *(const float4*)(wv + (size_t)(tr + lr) * 1024 + tc + t16 * 4);
            tle[lr][t16 * 4 + 0] = v.x;
            tle[lr][t16 * 4 + 1] = v.y;
            tle[lr][t16 * 4 + 2] = v.z;
            tle[lr][t16 * 4 + 3] = v.w;
        }
        __syncthreads();
#pragma unroll
        for (int j = 0; j < 4; ++j) {
            int orow = tq + j * 16;
            int oc = t16 * 4;
            half4_t h;
#pragma unroll
            for (int i = 0; i < 4; ++i) h[i] = (_Float16)tle[oc + i][orow];
            *(half4_t*)(vTh + (size_t)(tc + orow) * 1024 + tr + oc) = h;
        }
    }
}

// ---------------- split-f16 GEMM (3-MFMA, 16x16x32), 128x128 (M' partials) ----------------
template <bool OUTF32>
__global__ __launch_bounds__(256) void gemm_split(
    const _Float16* __restrict__ Ah, const _Float16* __restrict__ Al, size_t az,
    const _Float16* __restrict__ Bh, const _Float16* __restrict__ Bl, size_t bz,
    float* __restrict__ Cf, size_t cz, int ldc,
    _Float16* __restrict__ Oh, _Float16* __restrict__ Ol, size_t oz, int ldo,
    int lda, int ldb, int K)
{
    __shared__ __align__(16) _Float16 sAh[BM][BK], sAl[BM][BK];
    __shared__ __align__(16) _Float16 sBh[BN][BK], sBl[BN][BK];

    const int tid = threadIdx.x;
    const int wave = tid >> 6, lane = tid & 63;
    const int wm = (wave >> 1) * 64, wn = (wave & 1) * 64;
    const int lrow = lane & 15, quad = lane >> 4;
    const int bm = blockIdx.y * BM, bn = blockIdx.x * BN;
    const int z = blockIdx.z;

    const _Float16* pAh = Ah + (size_t)z * az;
    const _Float16* pAl = Al + (size_t)z * az;
    const _Float16* pBh = Bh + (size_t)z * bz;
    const _Float16* pBl = Bl + (size_t)z * bz;

    const int r0 = wave * 32 + (lane >> 2);
    const int kofs = (lane & 3) * 8;
    const size_t a0o = (size_t)(bm + r0) * lda + kofs;
    const size_t a1o = a0o + (size_t)16 * lda;
    const size_t b0o = (size_t)(bn + r0) * ldb + kofs;
    const size_t b1o = b0o + (size_t)16 * ldb;
    _Float16* lA0 = &sAh[r0][kofs];
    _Float16* lA1 = &sAh[r0 + 16][kofs];
    _Float16* lAl0 = &sAl[r0][kofs];
    _Float16* lAl1 = &sAl[r0 + 16][kofs];
    _Float16* lB0 = &sBh[r0][kofs];
    _Float16* lB1 = &sBh[r0 + 16][kofs];
    _Float16* lBl0 = &sBl[r0][kofs];
    _Float16* lBl1 = &sBl[r0 + 16][kofs];

    f32x4 acc[4][4];
#pragma unroll
    for (int i = 0; i < 4; ++i)
#pragma unroll
        for (int j = 0; j < 4; ++j) acc[i][j] = 0.0f;

    for (int k0 = 0; k0 < K; k0 += BK) {
        gl_lds16(pAh + a0o + k0, lA0);
        gl_lds16(pAh + a1o + k0, lA1);
        gl_lds16(pAl + a0o + k0, lAl0);
        gl_lds16(pAl + a1o + k0, lAl1);
        gl_lds16(pBh + b0o + k0, lB0);
        gl_lds16(pBh + b1o + k0, lB1);
        gl_lds16(pBl + b0o + k0, lBl0);
        gl_lds16(pBl + b1o + k0, lBl1);
        __syncthreads();

        half8_t a0[4], a1[4], b0[4], b1[4];
#pragma unroll
        for (int mt = 0; mt < 4; ++mt) {
            a0[mt] = *(const half8_t*)&sAh[wm + mt * 16 + lrow][quad * 8];
            a1[mt] = *(const half8_t*)&sAl[wm + mt * 16 + lrow][quad * 8];
        }
#pragma unroll
        for (int nt = 0; nt < 4; ++nt) {
            b0[nt] = *(const half8_t*)&sBh[wn + nt * 16 + lrow][quad * 8];
            b1[nt] = *(const half8_t*)&sBl[wn + nt * 16 + lrow][quad * 8];
        }
#pragma unroll
        for (int mt = 0; mt < 4; ++mt)
#pragma unroll
            for (int nt = 0; nt < 4; ++nt) {
                acc[mt][nt] = __builtin_amdgcn_mfma_f32_16x16x32_f16(a0[mt], b0[nt], acc[mt][nt], 0, 0, 0);
                acc[mt][nt] = __builtin_amdgcn_mfma_f32_16x16x32_f16(a0[mt], b1[nt], acc[mt][nt], 0, 0, 0);
                acc[mt][nt] = __builtin_amdgcn_mfma_f32_16x16x32_f16(a1[mt], b0[nt], acc[mt][nt], 0, 0, 0);
            }
        __syncthreads();
    }

#pragma unroll
    for (int mt = 0; mt < 4; ++mt)
#pragma unroll
        for (int nt = 0; nt < 4; ++nt)
#pragma unroll
            for (int r = 0; r < 4; ++r) {
                int gm = bm + wm + mt * 16 + quad * 4 + r;
                int gn = bn + wn + nt * 16 + lrow;
                float v = acc[mt][nt][r];
                if (OUTF32) {
                    Cf[(size_t)z * cz + (size_t)gm * ldc + gn] = v;
                } else {
                    _Float16 h = (_Float16)v;
                    Oh[(size_t)z * oz + (size_t)gm * ldo + gn] = h;
                    Ol[(size_t)z * oz + (size_t)gm * ldo + gn] = (_Float16)(v - (float)h);
                }
            }
}

// ---------------- M' partial reduce + split: Mh/Ml = split(sum_z P[z]) ----------------
__global__ __launch_bounds__(256) void reduce_m_kernel(
    const float* __restrict__ P, _Float16* __restrict__ Mh, _Float16* __restrict__ Ml)
{
    int i = blockIdx.x * 256 + threadIdx.x;  // float4 index over 1024*1024
    float4 a = ((const float4*)P)[i];
    float4 b = ((const float4*)(P + 1048576))[i];
    float4 c = ((const float4*)(P + 2097152))[i];
    float4 d = ((const float4*)(P + 3145728))[i];
    float s[4] = {a.x + b.x + c.x + d.x, a.y + b.y + c.y + d.y,
                  a.z + b.z + c.z + d.z, a.w + b.w + c.w + d.w};
    half4_t h, l;
#pragma unroll
    for (int j = 0; j < 4; ++j) {
        _Float16 hh = (_Float16)s[j];
        h[j] = hh;
        l[j] = (_Float16)(s[j] - (float)hh);
    }
    ((half4_t*)Mh)[i] = h;
    ((half4_t*)Ml)[i] = l;
}

// ---------------- scores: combined 3-MFMA, 256x256 tile, 8 waves, K=1024 ----------------
// EXACT r18 (best measured 96.5 µs): reg-staged (1-step gap), conflict-free
// chunk swizzle F=row*4+(j^((row>>1)&3)), single barrier/step, 2 slots per
// plane (128 KB LDS), 3 MFMA per frag-quad adjacent order.
#define NSTEPS 32  // 1024 / 32

__global__ __launch_bounds__(512, 2) void scores_c3(
    const _Float16* __restrict__ yh, const _Float16* __restrict__ yl,
    const _Float16* __restrict__ xh, const _Float16* __restrict__ xl,
    float* __restrict__ Cf)
{
    __shared__ __align__(16) _Float16 sAh[2][8192], sAl[2][8192];  // 64KB
    __shared__ __align__(16) _Float16 sBh[2][8192], sBl[2][8192];  // 64KB

    const int tid = threadIdx.x;
    const int wave = tid >> 6, lane = tid & 63;
    const int wm = (wave >> 2) * 128;   // 2 wave-rows
    const int wn = (wave & 3) * 64;     // 4 wave-cols
    const int l15 = lane & 15, jq = lane >> 4;

    // XCD-chunked bijective swizzle (256 blocks)
    const int flat = blockIdx.x + (blockIdx.y << 3) + (blockIdx.z << 6);
    const int work = ((flat & 7) << 5) + (flat >> 3);
    const int z = work >> 6;
    const int bm = ((work >> 3) & 7) * 256;
    const int bn = (work & 7) * 256;

    const _Float16* Ah = yh + ((size_t)z * 2048 + bm) * 1024;
    const _Float16* Al = yl + ((size_t)z * 2048 + bm) * 1024;
    const _Float16* Bh = xh + ((size_t)z * 2048 + bn) * 1024;
    const _Float16* Bl = xl + ((size_t)z * 2048 + bn) * 1024;

    int a_off0, b_off0;
    {
        int row = wm + l15;
        a_off0 = (row * 4 + (jq ^ ((row >> 1) & 3))) * 16;
        row = wn + l15;
        b_off0 = (row * 4 + (jq ^ ((row >> 1) & 3))) * 16;
    }
    asm volatile("" : "+v"(a_off0), "+v"(b_off0));
    int row0 = tid >> 2;
    int j0 = (tid & 3) ^ ((row0 >> 1) & 3);
    int g0 = row0 * 2048 + j0 * 16;   // global byte offset, chunk c0
    int g1 = g0 + 262144;             // +128 rows, chunk c1
    int wb0 = tid * 16;               // LDS byte offset (chunk c1 = +8192 imm)
    asm volatile("" : "+v"(g0), "+v"(g1), "+v"(wb0));

    // in-flight staging regs: 4 planes x 2 chunks (32 VGPR), 1 step ahead
    f32x4 rAh[2], rAl[2], rBh[2], rBl[2];

    auto ISSUE = [&](int t) {
        const char* pa = (const char*)(Ah + t * 32);
        const char* pl = (const char*)(Al + t * 32);
        const char* pb = (const char*)(Bh + t * 32);
        const char* pq = (const char*)(Bl + t * 32);
        rAh[0] = *(const f32x4*)(pa + g0); rAh[1] = *(const f32x4*)(pa + g1);
        rAl[0] = *(const f32x4*)(pl + g0); rAl[1] = *(const f32x4*)(pl + g1);
        rBh[0] = *(const f32x4*)(pb + g0); rBh[1] = *(const f32x4*)(pb + g1);
        rBl[0] = *(const f32x4*)(pq + g0); rBl[1] = *(const f32x4*)(pq + g1);
    };
    auto WRITE = [&](int p) {
        *(f32x4*)((char*)sAh[p] + wb0) = rAh[0];
        *(f32x4*)((char*)sAh[p] + wb0 + 8192) = rAh[1];
        *(f32x4*)((char*)sAl[p] + wb0) = rAl[0];
        *(f32x4*)((char*)sAl[p] + wb0 + 8192) = rAl[1];
        *(f32x4*)((char*)sBh[p] + wb0) = rBh[0];
        *(f32x4*)((char*)sBh[p] + wb0 + 8192) = rBh[1];
        *(f32x4*)((char*)sBl[p] + wb0) = rBl[0];
        *(f32x4*)((char*)sBl[p] + wb0 + 8192) = rBl[1];
    };

    f32x4 acc[8][4];
#pragma unroll
    for (int i = 0; i < 8; ++i)
#pragma unroll
        for (int j = 0; j < 4; ++j) acc[i][j] = 0.0f;

    auto STEP = [&](int p, int tn) {
        half8_t bhf[4], blf[4];
#pragma unroll
        for (int n = 0; n < 4; ++n) {
            bhf[n] = *(const half8_t*)((const char*)sBh[p] + b_off0 + n * 1024);
            blf[n] = *(const half8_t*)((const char*)sBl[p] + b_off0 + n * 1024);
        }
        WRITE(p ^ 1);
        ISSUE(tn);
        __builtin_amdgcn_s_setprio(1);
#pragma unroll
        for (int m = 0; m < 8; ++m) {
            half8_t ahf = *(const half8_t*)((const char*)sAh[p] + a_off0 + m * 1024);
            half8_t alf = *(const half8_t*)((const char*)sAl[p] + a_off0 + m * 1024);
#pragma unroll
            for (int n = 0; n < 4; ++n) {
                acc[m][n] = __builtin_amdgcn_mfma_f32_16x16x32_f16(ahf, bhf[n], acc[m][n], 0, 0, 0);
                acc[m][n] = __builtin_amdgcn_mfma_f32_16x16x32_f16(ahf, blf[n], acc[m][n], 0, 0, 0);
                acc[m][n] = __builtin_amdgcn_mfma_f32_16x16x32_f16(alf, bhf[n], acc[m][n], 0, 0, 0);
            }
        }
        __builtin_amdgcn_s_setprio(0);
        __builtin_amdgcn_s_barrier();
    };

    // prologue: stage step0 into slot0; leave step1 in regs (written @ s=0).
    ISSUE(0);
    WRITE(0);
    ISSUE(1);
    __syncthreads();

    for (int s = 0; s < NSTEPS; s += 2) {
        const int t2 = (s + 2 < NSTEPS) ? s + 2 : NSTEPS - 1;
        const int t3 = (s + 3 < NSTEPS) ? s + 3 : NSTEPS - 1;
        STEP(0, t2);  // even step: read slot0, fill slot1
        STEP(1, t3);  // odd step:  read slot1, fill slot0
    }

    // epilogue: fp32 C scatter (same mapping as verified gemm_split)
    float* C = Cf + (size_t)z * 2048 * 2048;
#pragma unroll
    for (int mi = 0; mi < 8; ++mi)
#pragma unroll
        for (int ni = 0; ni < 4; ++ni) {
            int gm0 = bm + wm + mi * 16 + jq * 4;
            int gn = bn + wn + ni * 16 + l15;
#pragma unroll
            for (int r = 0; r < 4; ++r)
                C[(size_t)(gm0 + r) * 2048 + gn] = acc[mi][ni][r];
        }
}

// ---------------- merged y-proj (split) + v-proj (plain) kernel ----------------
__global__ __launch_bounds__(256) void yv_kernel(
    const _Float16* __restrict__ xh, const _Float16* __restrict__ xl,
    const _Float16* __restrict__ Mh, const _Float16* __restrict__ Ml,
    const _Float16* __restrict__ wvTh,
    _Float16* __restrict__ yh, _Float16* __restrict__ yl,
    _Float16* __restrict__ vT)
{
    __shared__ __align__(16) char buf[128 * 132 * 2];  // 33792 B

    const int tid = threadIdx.x;
    const int wave = tid >> 6, lane = tid & 63;
    const int wm = (wave >> 1) * 64, wn = (wave & 1) * 64;
    const int lrow = lane & 15, quad = lane >> 4;
    const int bm = blockIdx.y * BM, bn = blockIdx.x * BN;
    const bool vrole = (blockIdx.z != 0);

    const int r0 = wave * 32 + (lane >> 2);
    const int kofs = (lane & 3) * 8;
    const size_t a0o = (size_t)(bm + r0) * 1024 + kofs;
    const size_t a1o = a0o + (size_t)16 * 1024;
    const size_t b0o = (size_t)(bn + r0) * 1024 + kofs;
    const size_t b1o = b0o + (size_t)16 * 1024;

    f32x4 acc[4][4];
#pragma unroll
    for (int i = 0; i < 4; ++i)
#pragma unroll
        for (int j = 0; j < 4; ++j) acc[i][j] = 0.0f;

    _Float16* tle = (_Float16*)buf;

    if (!vrole) {
        _Float16* sAh = (_Float16*)buf;
        _Float16* sAl = (_Float16*)(buf + 8192);
        _Float16* sBh = (_Float16*)(buf + 16384);
        _Float16* sBl = (_Float16*)(buf + 24576);
        _Float16* lA0 = sAh + r0 * BK + kofs;
        _Float16* lA1 = sAh + (r0 + 16) * BK + kofs;
        _Float16* lAl0 = sAl + r0 * BK + kofs;
        _Float16* lAl1 = sAl + (r0 + 16) * BK + kofs;
        _Float16* lB0 = sBh + r0 * BK + kofs;
        _Float16* lB1 = sBh + (r0 + 16) * BK + kofs;
        _Float16* lBl0 = sBl + r0 * BK + kofs;
        _Float16* lBl1 = sBl + (r0 + 16) * BK + kofs;

        for (int k0 = 0; k0 < 1024; k0 += BK) {
            gl_lds16(xh + a0o + k0, lA0);
            gl_lds16(xh + a1o + k0, lA1);
            gl_lds16(xl + a0o + k0, lAl0);
            gl_lds16(xl + a1o + k0, lAl1);
            gl_lds16(Mh + b0o + k0, lB0);
            gl_lds16(Mh + b1o + k0, lB1);
            gl_lds16(Ml + b0o + k0, lBl0);
            gl_lds16(Ml + b1o + k0, lBl1);
            __syncthreads();

            half8_t a0[4], a1[4], b0[4], b1[4];
#pragma unroll
            for (int mt = 0; mt < 4; ++mt) {
                a0[mt] = *(const half8_t*)(sAh + (wm + mt * 16 + lrow) * BK + quad * 8);
                a1[mt] = *(const half8_t*)(sAl + (wm + mt * 16 + lrow) * BK + quad * 8);
            }
#pragma unroll
            for (int nt = 0; nt < 4; ++nt) {
                b0[nt] = *(const half8_t*)(sBh + (wn + nt * 16 + lrow) * BK + quad * 8);
                b1[nt] = *(const half8_t*)(sBl + (wn + nt * 16 + lrow) * BK + quad * 8);
            }
#pragma unroll
            for (int mt = 0; mt < 4; ++mt)
#pragma unroll
                for (int nt = 0; nt < 4; ++nt) {
                    acc[mt][nt] = __builtin_amdgcn_mfma_f32_16x16x32_f16(a0[mt], b0[nt], acc[mt][nt], 0, 0, 0);
                    acc[mt][nt] = __builtin_amdgcn_mfma_f32_16x16x32_f16(a0[mt], b1[nt], acc[mt][nt], 0, 0, 0);
                    acc[mt][nt] = __builtin_amdgcn_mfma_f32_16x16x32_f16(a1[mt], b0[nt], acc[mt][nt], 0, 0, 0);
                }
            __syncthreads();
        }

#pragma unroll
        for (int pass = 0; pass < 2; ++pass) {
            if (pass) __syncthreads();
#pragma unroll
            for (int mt = 0; mt < 4; ++mt)
#pragma unroll
                for (int nt = 0; nt < 4; ++nt) {
                    int rloc = wm + mt * 16 + quad * 4;
                    int cloc = wn + nt * 16 + lrow;
#pragma unroll
                    for (int r = 0; r < 4; ++r) {
                        float v = acc[mt][nt][r];
                        _Float16 h = (_Float16)v;
                        tle[(rloc + r) * 132 + cloc] =
                            pass == 0 ? h : (_Float16)(v - (float)h);
                    }
                }
            __syncthreads();
            _Float16* dst = pass == 0 ? yh : yl;
#pragma unroll
            for (int i = 0; i < 8; ++i) {
                int flat = i * 256 + tid;
                int rloc = flat >> 4, c = (flat & 15) * 8;
                half8_t o8;
#pragma unroll
                for (int j = 0; j < 8; ++j) o8[j] = tle[rloc * 132 + c + j];
                *(half8_t*)(dst + (size_t)(bm + rloc) * 1024 + bn + c) = o8;
            }
        }
    } else {
        _Float16* sA = (_Float16*)buf;
        _Float16* sB = (_Float16*)(buf + 8192);
        _Float16* lA0 = sA + r0 * BK + kofs;
        _Float16* lA1 = sA + (r0 + 16) * BK + kofs;
        _Float16* lB0 = sB + r0 * BK + kofs;
        _Float16* lB1 = sB + (r0 + 16) * BK + kofs;

        for (int k0 = 0; k0 < 1024; k0 += BK) {
            gl_lds16(xh + a0o + k0, lA0);
            gl_lds16(xh + a1o + k0, lA1);
            gl_lds16(wvTh + b0o + k0, lB0);
            gl_lds16(wvTh + b1o + k0, lB1);
            __syncthreads();

            half8_t a0[4], b0[4];
#pragma unroll
            for (int mt = 0; mt < 4; ++mt)
                a0[mt] = *(const half8_t*)(sA + (wm + mt * 16 + lrow) * BK + quad * 8);
#pragma unroll
            for (int nt = 0; nt < 4; ++nt)
                b0[nt] = *(const half8_t*)(sB + (wn + nt * 16 + lrow) * BK + quad * 8);
#pragma unroll
            for (int mt = 0; mt < 4; ++mt)
#pragma unroll
                for (int nt = 0; nt < 4; ++nt)
                    acc[mt][nt] = __builtin_amdgcn_mfma_f32_16x16x32_f16(a0[mt], b0[nt], acc[mt][nt], 0, 0, 0);
            __syncthreads();
        }

#pragma unroll
        for (int mt = 0; mt < 4; ++mt)
#pragma unroll
            for (int nt = 0; nt < 4; ++nt) {
                int t0 = wm + mt * 16 + quad * 4;
                int e_l = wn + nt * 16 + lrow;
                half4_t o;
#pragma unroll
                for (int r = 0; r < 4; ++r) o[r] = (_Float16)acc[mt][nt][r];
                *(half4_t*)(tle + e_l * 132 + t0) = o;
            }
        __syncthreads();
        const int b = bm >> 11, tb = bm & 2047;
#pragma unroll
        for (int i = 0; i < 8; ++i) {
            int flat = i * 256 + tid;
            int e_l = flat >> 4, c = (flat & 15) * 8;
            half8_t o8;
#pragma unroll
            for (int j = 0; j < 8; ++j) o8[j] = tle[e_l * 132 + c + j];
            *(half8_t*)(vT + ((size_t)b << 21) + (size_t)(bn + e_l) * 2048 + tb + c) = o8;
        }
    }
}

// ---------------- plain-f16 GEMM (16x16x32), 128x128, 256 thr (PV) ----------------
__global__ __launch_bounds__(256) void gemm_plain(
    const _Float16* __restrict__ Ag, size_t az,
    const _Float16* __restrict__ Bg, size_t bz,
    float* __restrict__ Cf, size_t cz, int ldc,
    int lda, int ldb, int K)
{
    __shared__ __align__(16) _Float16 sA[BM][BK], sB[BN][BK];

    const int tid = threadIdx.x;
    const int wave = tid >> 6, lane = tid & 63;
    const int wm = (wave >> 1) * 64, wn = (wave & 1) * 64;
    const int lrow = lane & 15, quad = lane >> 4;
    const int bm = blockIdx.y * BM, bn = blockIdx.x * BN;
    const int z = blockIdx.z;

    const _Float16* pA = Ag + (size_t)z * az;
    const _Float16* pB = Bg + (size_t)z * bz;

    const int r0 = wave * 32 + (lane >> 2);
    const int kofs = (lane & 3) * 8;
    const size_t a0o = (size_t)(bm + r0) * lda + kofs;
    const size_t a1o = a0o + (size_t)16 * lda;
    const size_t b0o = (size_t)(bn + r0) * ldb + kofs;
    const size_t b1o = b0o + (size_t)16 * ldb;
    _Float16* lA0 = &sA[r0][kofs];
    _Float16* lA1 = &sA[r0 + 16][kofs];
    _Float16* lB0 = &sB[r0][kofs];
    _Float16* lB1 = &sB[r0 + 16][kofs];

    f32x4 acc[4][4];
#pragma unroll
    for (int i = 0; i < 4; ++i)
#pragma unroll
        for (int j = 0; j < 4; ++j) acc[i][j] = 0.0f;

    for (int k0 = 0; k0 < K; k0 += BK) {
        gl_lds16(pA + a0o + k0, lA0);
        gl_lds16(pA + a1o + k0, lA1);
        gl_lds16(pB + b0o + k0, lB0);
        gl_lds16(pB + b1o + k0, lB1);
        __syncthreads();

        half8_t a0[4], b0[4];
#pragma unroll
        for (int mt = 0; mt < 4; ++mt)
            a0[mt] = *(const half8_t*)&sA[wm + mt * 16 + lrow][quad * 8];
#pragma unroll
        for (int nt = 0; nt < 4; ++nt)
            b0[nt] = *(const half8_t*)&sB[wn + nt * 16 + lrow][quad * 8];
#pragma unroll
        for (int mt = 0; mt < 4; ++mt)
#pragma unroll
            for (int nt = 0; nt < 4; ++nt)
                acc[mt][nt] = __builtin_amdgcn_mfma_f32_16x16x32_f16(a0[mt], b0[nt], acc[mt][nt], 0, 0, 0);
        __syncthreads();
    }

#pragma unroll
    for (int mt = 0; mt < 4; ++mt)
#pragma unroll
        for (int nt = 0; nt < 4; ++nt) {
            int gm0 = bm + wm + mt * 16 + quad * 4;
            int gn = bn + wn + nt * 16 + lrow;
#pragma unroll
            for (int r = 0; r < 4; ++r)
                Cf[(size_t)z * cz + (size_t)(gm0 + r) * ldc + gn] = acc[mt][nt][r];
        }
}

// ---------------- softmax: fp32 scores row -> f16 P row, in place ----------------
__global__ __launch_bounds__(256) void softmax_kernel(float* __restrict__ S)
{
    float* row = S + (size_t)blockIdx.x * 2048;
    float4* r4 = (float4*)row;
    const int tid = threadIdx.x;
    const int wave = tid >> 6, lane = tid & 63;

    float4 a = r4[tid], b = r4[tid + 256];
    float m = fmaxf(fmaxf(fmaxf(a.x, a.y), fmaxf(a.z, a.w)),
                    fmaxf(fmaxf(b.x, b.y), fmaxf(b.z, b.w)));
#pragma unroll
    for (int o = 32; o; o >>= 1) m = fmaxf(m, __shfl_xor(m, o));
    __shared__ float redm[4];
    __shared__ float reds[4];
    if (lane == 0) redm[wave] = m;
    __syncthreads();
    m = fmaxf(fmaxf(redm[0], redm[1]), fmaxf(redm[2], redm[3]));

    a.x = __expf(a.x - m); a.y = __expf(a.y - m);
    a.z = __expf(a.z - m); a.w = __expf(a.w - m);
    b.x = __expf(b.x - m); b.y = __expf(b.y - m);
    b.z = __expf(b.z - m); b.w = __expf(b.w - m);

    float s = a.x + a.y + a.z + a.w + b.x + b.y + b.z + b.w;
#pragma unroll
    for (int o = 32; o; o >>= 1) s += __shfl_xor(s, o);
    if (lane == 0) reds[wave] = s;
    __syncthreads();
    s = reds[0] + reds[1] + reds[2] + reds[3];

    float inv = 1.0f / s;
    _Float16* o16 = (_Float16*)row;
    half4_t ha, hb;
    ha[0] = (_Float16)(a.x * inv); ha[1] = (_Float16)(a.y * inv);
    ha[2] = (_Float16)(a.z * inv); ha[3] = (_Float16)(a.w * inv);
    hb[0] = (_Float16)(b.x * inv); hb[1] = (_Float16)(b.y * inv);
    hb[2] = (_Float16)(b.z * inv); hb[3] = (_Float16)(b.w * inv);
    ((half4_t*)o16)[tid] = ha;
    ((half4_t*)o16)[tid + 256] = hb;
}

extern "C" void kernel_launch(void* const* d_in, const int* in_sizes, int n_in,
                              void* d_out, int out_size, void* d_ws, size_t ws_size,
                              hipStream_t stream)
{
    const float* x  = (const float*)d_in[0];
    const float* wq = (const float*)d_in[1];
    const float* wk = (const float*)d_in[2];
    const float* wv = (const float*)d_in[3];
    float* out = (float*)d_out;

    const int S = 2048, D = 1024;
    char* ws = (char*)d_ws;

    // ws layout (bytes); high-water 158 MB
    _Float16* xh   = (_Float16*)(ws);                  // 16 MB
    _Float16* xl   = (_Float16*)(ws + (16ull << 20));  // 16 MB
    _Float16* yh   = (_Float16*)(ws + (32ull << 20));  // 16 MB
    _Float16* yl   = (_Float16*)(ws + (48ull << 20));  // 16 MB
    _Float16* vT   = (_Float16*)(ws + (64ull << 20));  // 16 MB [4][1024][2048]
    _Float16* wqh  = (_Float16*)(ws + (80ull << 20));  // 2 MB (natural layout)
    _Float16* wql  = (_Float16*)(ws + (82ull << 20));  // 2 MB
    _Float16* wkh  = (_Float16*)(ws + (84ull << 20));  // 2 MB
    _Float16* wkl  = (_Float16*)(ws + (86ull << 20));  // 2 MB
    _Float16* wvTh = (_Float16*)(ws + (88ull << 20));  // 2 MB (transposed)
    _Float16* Mh   = (_Float16*)(ws + (90ull << 20));  // 2 MB  M' = Wk@Wq^T
    _Float16* Ml   = (_Float16*)(ws + (92ull << 20));  // 2 MB
    float*    sc   = (float*)(ws + (94ull << 20));     // 64 MB scores
    float*    mp   = (float*)(ws + (94ull << 20));     // 16 MB M' partials
                                                       // (overlaps sc; consumed
                                                       // before scores writes)

    // 1) all conversions, flat grid
    conv_all_kernel<<<dim3(10496), dim3(256), 0, stream>>>(
        x, wq, wk, wv, xh, xl, wqh, wql, wkh, wkl, wvTh);

    // 2a) M' partials: K=1024 split x4 (z-stride 256 elems), full-GPU grid
    gemm_split<true><<<dim3(D / BN, D / BM, 4), dim3(256), 0, stream>>>(
        wkh, wkl, 256, wqh, wql, 256, mp, (size_t)D * D, D,
        nullptr, nullptr, 0, 0, D, D, 256);

    // 2b) reduce partials -> split Mh/Ml
    reduce_m_kernel<<<dim3(1024), dim3(256), 0, stream>>>(mp, Mh, Ml);

    // 3) y-proj (split, coalesced epilogue) + v-proj (plain, coalesced vT)
    yv_kernel<<<dim3(D / BN, 8192 / BM, 2), dim3(256), 0, stream>>>(
        xh, xl, Mh, Ml, wvTh, yh, yl, vT);

    // 4) scores: combined 3-MFMA, 256² tile, 8 waves, K=1024, reg-staged
    scores_c3<<<dim3(S / 256, S / 256, 4), dim3(512), 0, stream>>>(
        yh, yl, xh, xl, sc);

    // 5) softmax rows, f16 P written in place (row stride stays 8192 B)
    softmax_kernel<<<dim3(4 * S), dim3(256), 0, stream>>>(sc);

    // 6) out = P @ v: A=P f16 (lda=4096 f16 elems), B=vT f16, out fp32
    gemm_plain<<<dim3(D / BN, S / BM, 4), dim3(256), 0, stream>>>(
        (const _Float16*)sc, (size_t)S * 4096, vT, (size_t)D * S,
        out, (size_t)S * D, D, 4096, S, S);
}